// Round 1
// baseline (7652.085 us; speedup 1.0000x reference)
//
#include <hip/hip_runtime.h>
#include <cmath>

// GRU scan: T=128 steps, B=512 batch, D=512 in, H=512 hidden.
// Per step t:
//   h_eff = reset[t] ? 0 : h_{t-1}
//   gi    = x_t @ Wi + bi                  (Wi: [D, 3H] = [ir|iz|in])
//   grz   = h_eff @ Wh_rz                  (Wh_rz: [H, 2H] = [hr|hz])
//   r = sigmoid(gi_r + grz_r); z = sigmoid(gi_z + grz_z)
//   n = tanh(gi_n + r * (h_eff @ Wh_n + bh_n))
//   h_t = (1-z)*n + z*h_eff
// Output: d_out = [hT (B*H) | ys (T*B*H)], ys[t] == h_t.
// h_prev for step t is read from ys[t-1] (h0 for t=0) -> no scratch needed.

#define T_STEPS 128
#define B_SZ 512
#define D_SZ 512
#define H_SZ 512

constexpr int BM = 32, BN = 32, BK = 32;
constexpr int LDT = BM + 4; // padded LDS stride: 36 words = 144 B (8B/16B aligned)

__device__ __forceinline__ float sigmoidf_(float x) {
    return 1.0f / (1.0f + __expf(-x));
}

__global__ __launch_bounds__(256, 1) void gru_step(
    const float* __restrict__ x,       // [B][D]   ins + t*B*D
    const int*   __restrict__ rst,     // [B]      resets + t*B (bool as int32)
    const float* __restrict__ h_prev,  // [B][H]
    const float* __restrict__ Wi,      // [D][3H]
    const float* __restrict__ bi,      // [3H]
    const float* __restrict__ Wh_rz,   // [H][2H]
    const float* __restrict__ Wh_n,    // [H][H]
    const float* __restrict__ bh_n,    // [H]
    float* __restrict__ h_out,         // [B][H]  = ys + t*B*H
    float* __restrict__ hT_out)        // [B][H] or nullptr (written on last step)
{
    __shared__ float xs[BK][LDT];      // x^T tile:  xs[k][m]
    __shared__ float hs[BK][LDT];      // h^T tile (reset-masked)
    __shared__ float wt[6][BK][LDT];   // weight tiles wt[g][k][n]: g=ir,iz,in,hr,hz,hn

    const int tid = threadIdx.x;
    const int bm0 = blockIdx.x * BM;   // batch-row base
    const int jn0 = blockIdx.y * BN;   // hidden-col base

    // loader mapping: 256 threads each move one float4 per tile
    const int lr = tid >> 3;           // 0..31
    const int lc = (tid & 7) << 2;     // 0,4,...,28

    // compute mapping: 16x16 threads, 2x2 outputs each
    const int ty   = tid >> 4;         // 0..15
    const int tx   = tid & 15;         // 0..15
    const int row0 = 2 * ty;           // batch row within tile
    const int col0 = 2 * tx;           // hidden col within tile

    float aR[2][2] = {{0.f,0.f},{0.f,0.f}};
    float aZ[2][2] = {{0.f,0.f},{0.f,0.f}};
    float aN[2][2] = {{0.f,0.f},{0.f,0.f}};
    float hR[2][2] = {{0.f,0.f},{0.f,0.f}};
    float hZ[2][2] = {{0.f,0.f},{0.f,0.f}};
    float hN[2][2] = {{0.f,0.f},{0.f,0.f}};

    const int   ldrow   = bm0 + lr;
    const bool  rmaskld = (rst[ldrow] != 0);
    const float* xrow  = x      + (size_t)ldrow * D_SZ;
    const float* hrow  = h_prev + (size_t)ldrow * H_SZ;

    for (int k0 = 0; k0 < D_SZ; k0 += BK) {
        // ---- global loads (coalesced float4) ----
        float4 xv = *(const float4*)(xrow + k0 + lc);
        float4 hv = *(const float4*)(hrow + k0 + lc);
        if (rmaskld) { hv.x = 0.f; hv.y = 0.f; hv.z = 0.f; hv.w = 0.f; }
        const float* wi_row = Wi    + (size_t)(k0 + lr) * (3 * H_SZ);
        const float* wh_row = Wh_rz + (size_t)(k0 + lr) * (2 * H_SZ);
        float4 w0v = *(const float4*)(wi_row + jn0 + lc);
        float4 w1v = *(const float4*)(wi_row + H_SZ + jn0 + lc);
        float4 w2v = *(const float4*)(wi_row + 2 * H_SZ + jn0 + lc);
        float4 w3v = *(const float4*)(wh_row + jn0 + lc);
        float4 w4v = *(const float4*)(wh_row + H_SZ + jn0 + lc);
        float4 w5v = *(const float4*)(Wh_n + (size_t)(k0 + lr) * H_SZ + jn0 + lc);

        __syncthreads();   // previous iteration's LDS reads done

        // x,h scattered transposed; weights stored straight (k-major)
        xs[lc + 0][lr] = xv.x; xs[lc + 1][lr] = xv.y;
        xs[lc + 2][lr] = xv.z; xs[lc + 3][lr] = xv.w;
        hs[lc + 0][lr] = hv.x; hs[lc + 1][lr] = hv.y;
        hs[lc + 2][lr] = hv.z; hs[lc + 3][lr] = hv.w;
        *(float4*)&wt[0][lr][lc] = w0v;
        *(float4*)&wt[1][lr][lc] = w1v;
        *(float4*)&wt[2][lr][lc] = w2v;
        *(float4*)&wt[3][lr][lc] = w3v;
        *(float4*)&wt[4][lr][lc] = w4v;
        *(float4*)&wt[5][lr][lc] = w5v;

        __syncthreads();

        #pragma unroll
        for (int kk = 0; kk < BK; ++kk) {
            float2 xa = *(const float2*)&xs[kk][row0];
            float2 ha = *(const float2*)&hs[kk][row0];
            float2 w0 = *(const float2*)&wt[0][kk][col0];
            float2 w1 = *(const float2*)&wt[1][kk][col0];
            float2 w2 = *(const float2*)&wt[2][kk][col0];
            float2 w3 = *(const float2*)&wt[3][kk][col0];
            float2 w4 = *(const float2*)&wt[4][kk][col0];
            float2 w5 = *(const float2*)&wt[5][kk][col0];

            aR[0][0] = fmaf(xa.x, w0.x, aR[0][0]); aR[0][1] = fmaf(xa.x, w0.y, aR[0][1]);
            aR[1][0] = fmaf(xa.y, w0.x, aR[1][0]); aR[1][1] = fmaf(xa.y, w0.y, aR[1][1]);
            aZ[0][0] = fmaf(xa.x, w1.x, aZ[0][0]); aZ[0][1] = fmaf(xa.x, w1.y, aZ[0][1]);
            aZ[1][0] = fmaf(xa.y, w1.x, aZ[1][0]); aZ[1][1] = fmaf(xa.y, w1.y, aZ[1][1]);
            aN[0][0] = fmaf(xa.x, w2.x, aN[0][0]); aN[0][1] = fmaf(xa.x, w2.y, aN[0][1]);
            aN[1][0] = fmaf(xa.y, w2.x, aN[1][0]); aN[1][1] = fmaf(xa.y, w2.y, aN[1][1]);
            hR[0][0] = fmaf(ha.x, w3.x, hR[0][0]); hR[0][1] = fmaf(ha.x, w3.y, hR[0][1]);
            hR[1][0] = fmaf(ha.y, w3.x, hR[1][0]); hR[1][1] = fmaf(ha.y, w3.y, hR[1][1]);
            hZ[0][0] = fmaf(ha.x, w4.x, hZ[0][0]); hZ[0][1] = fmaf(ha.x, w4.y, hZ[0][1]);
            hZ[1][0] = fmaf(ha.y, w4.x, hZ[1][0]); hZ[1][1] = fmaf(ha.y, w4.y, hZ[1][1]);
            hN[0][0] = fmaf(ha.x, w5.x, hN[0][0]); hN[0][1] = fmaf(ha.x, w5.y, hN[0][1]);
            hN[1][0] = fmaf(ha.y, w5.x, hN[1][0]); hN[1][1] = fmaf(ha.y, w5.y, hN[1][1]);
        }
    }

    // ---- epilogue: gates + write ----
    #pragma unroll
    for (int ii = 0; ii < 2; ++ii) {
        const int b = bm0 + row0 + ii;
        const bool rm = (rst[b] != 0);
        #pragma unroll
        for (int jj = 0; jj < 2; ++jj) {
            const int j = jn0 + col0 + jj;
            const float heff = rm ? 0.f : h_prev[(size_t)b * H_SZ + j];
            const float r = sigmoidf_(aR[ii][jj] + bi[j] + hR[ii][jj]);
            const float z = sigmoidf_(aZ[ii][jj] + bi[H_SZ + j] + hZ[ii][jj]);
            const float n = tanhf(aN[ii][jj] + bi[2 * H_SZ + j]
                                  + r * (hN[ii][jj] + bh_n[j]));
            const float v = (1.f - z) * n + z * heff;
            h_out[(size_t)b * H_SZ + j] = v;
            if (hT_out) hT_out[(size_t)b * H_SZ + j] = v;
        }
    }
}

extern "C" void kernel_launch(void* const* d_in, const int* in_sizes, int n_in,
                              void* d_out, int out_size, void* d_ws, size_t ws_size,
                              hipStream_t stream) {
    const float* h0     = (const float*)d_in[0];  // [B][H]
    const float* ins    = (const float*)d_in[1];  // [T][B][D]
    const int*   resets = (const int*)  d_in[2];  // [T][B] bool->int32
    const float* Wi     = (const float*)d_in[3];  // [D][3H]
    const float* bi     = (const float*)d_in[4];  // [3H]
    const float* Wh_rz  = (const float*)d_in[5];  // [H][2H]
    const float* Wh_n   = (const float*)d_in[6];  // [H][H]
    const float* bh_n   = (const float*)d_in[7];  // [H]

    float* out = (float*)d_out;
    float* hT  = out;                      // [B][H]
    float* ys  = out + (size_t)B_SZ * H_SZ;  // [T][B][H]

    dim3 grid(B_SZ / BM, H_SZ / BN);
    dim3 block(256);

    for (int t = 0; t < T_STEPS; ++t) {
        const float* hp = (t == 0) ? h0 : (ys + (size_t)(t - 1) * B_SZ * H_SZ);
        float* ho = ys + (size_t)t * B_SZ * H_SZ;
        gru_step<<<grid, block, 0, stream>>>(
            ins + (size_t)t * B_SZ * D_SZ,
            resets + (size_t)t * B_SZ,
            hp, Wi, bi, Wh_rz, Wh_n, bh_n,
            ho, (t == T_STEPS - 1) ? hT : nullptr);
    }
}

// Round 2
// 3551.455 us; speedup vs baseline: 2.1546x; 2.1546x over previous
//
#include <hip/hip_runtime.h>
#include <cmath>

// GRU scan, T=128 B=512 D=H=512.
// Strategy: f32-accuracy GEMMs on the f16 MFMA pipe via split-precision:
//   v = hi + lo/2048, hi = f16(v), lo = f16((v - hi)*2048)   (scale avoids f16 denormals)
//   a*b ~= ah*bh  +  (ah*bl~ + al~*bh)/2048     (3 MFMAs, 2 accumulators)
// Weights pre-transposed+split into d_ws once per call (K-major for B-frags).
// Per-step fused kernel: acc groups r,z = x@Wi_g + h@Wh_g ; gn = x@Wi_n ; hn = h@Wh_n.
// d_out = [hT (B*H) | ys (T*B*H)]; h_prev for step t read from ys[t-1] (h0 at t=0).

#define T_STEPS 128
#define B_SZ 512
#define HD 512          // hidden == input dim

typedef __attribute__((ext_vector_type(8))) _Float16 f16x8;
typedef __attribute__((ext_vector_type(4))) float f32x4;

#define MFMA16(a, b, c) __builtin_amdgcn_mfma_f32_16x16x32_f16((a), (b), (c), 0, 0, 0)

__device__ __forceinline__ float sigf_(float x) { return 1.0f / (1.0f + __expf(-x)); }
__device__ __forceinline__ float tanhf_(float x) { return 1.0f - 2.0f / (__expf(2.0f * x) + 1.0f); }

// ---------------------------------------------------------------------------
// Phase 0: transpose + split weights.
// WT[n][k], n in [0,3072): n<1536 -> Wi col n ; n>=1536 -> m=n-1536, g=m>>9, c=m&511:
//   g<2 -> Wh_rz[k][g*512+c] ; g==2 -> Wh_n[k][c]
// WT_hi = f16(v); WT_lo = f16((v - hi) * 2048)
// grid (8 k-tiles, 48 n-tiles), 64x64 tiles via LDS transpose.
// ---------------------------------------------------------------------------
__global__ __launch_bounds__(256) void conv_w(
    const float* __restrict__ Wi, const float* __restrict__ Wh_rz,
    const float* __restrict__ Wh_n,
    _Float16* __restrict__ WT_hi, _Float16* __restrict__ WT_lo)
{
    __shared__ float Tl[64][65];
    const int tid = threadIdx.x;
    const int k0 = blockIdx.x * 64;
    const int n0 = blockIdx.y * 64;

    const float* base;
    int stride;
    if (n0 < 1536) { base = Wi + n0; stride = 1536; }
    else {
        int m = n0 - 1536, g = m >> 9, c = m & 511;
        if (g < 2) { base = Wh_rz + g * 512 + c; stride = 1024; }
        else       { base = Wh_n + c;            stride = 512; }
    }

    // load 64(k) x 64(n) tile, coalesced along n
    #pragma unroll
    for (int p = 0; p < 4; ++p) {
        int kr = p * 16 + (tid >> 4);
        int nc = (tid & 15) * 4;
        float4 v = *(const float4*)(base + (size_t)(k0 + kr) * stride + nc);
        Tl[kr][nc + 0] = v.x; Tl[kr][nc + 1] = v.y;
        Tl[kr][nc + 2] = v.z; Tl[kr][nc + 3] = v.w;
    }
    __syncthreads();

    // write transposed: WT[n0+nr][k0+kc], 16 k per thread
    const int nr  = tid >> 2;
    const int kc0 = (tid & 3) * 16;
    f16x8 h0v, h1v, l0v, l1v;
    #pragma unroll
    for (int j = 0; j < 16; ++j) {
        float v = Tl[kc0 + j][nr];
        _Float16 th = (_Float16)v;
        _Float16 tl = (_Float16)((v - (float)th) * 2048.0f);
        if (j < 8) { h0v[j] = th; l0v[j] = tl; }
        else       { h1v[j - 8] = th; l1v[j - 8] = tl; }
    }
    size_t o = (size_t)(n0 + nr) * 512 + k0 + kc0;
    *(f16x8*)(WT_hi + o)     = h0v;
    *(f16x8*)(WT_hi + o + 8) = h1v;
    *(f16x8*)(WT_lo + o)     = l0v;
    *(f16x8*)(WT_lo + o + 8) = l1v;
}

// ---------------------------------------------------------------------------
// Per-step fused GRU kernel (split-f16 MFMA).
// grid (16 c-tiles, 8 m-tiles); block 256 = 4 waves (wm = w>>1 rows, wn = w&1 cols).
// Output tile 64 rows x 32 cols. BK = 32 (one K=32 MFMA chunk per step), 16 K-steps.
// LDS: A planes x_hi,x_lo,h_hi,h_lo [64][40]; B planes (6 strips x hi/lo) [32][40].
// Strips: 0 Wi_r, 1 Wi_z, 2 Wi_n, 3 Wh_r, 4 Wh_z, 5 Wh_n (plane 2s=hi, 2s+1=lo).
// acc[0..3] = main r,z,gn,hn ; acc[4..7] = corr (scale 2048).
// ---------------------------------------------------------------------------
__global__ __launch_bounds__(256, 1) void gru_fused(
    const float* __restrict__ x,       // [B][512]  x_t
    const int*   __restrict__ rst,     // [B]
    const float* __restrict__ hsrc,    // [B][512]  h_{t-1} (f32)
    const _Float16* __restrict__ WT_hi,// [3072][512]
    const _Float16* __restrict__ WT_lo,
    const float* __restrict__ bi,      // [1536]
    const float* __restrict__ bh_n,    // [512]
    float* __restrict__ hdst,          // [B][512]
    float* __restrict__ hT_out)        // [B][512] or nullptr
{
    __shared__ _Float16 A[4][64 * 40];
    __shared__ _Float16 Bs[12][32 * 40];

    const int tid = threadIdx.x;
    const int c0 = blockIdx.x * 32;
    const int m0 = blockIdx.y * 64;
    const int l  = tid & 63;
    const int w  = tid >> 6;
    const int wm = w >> 1, wn = w & 1;
    const int lr  = l & 15;
    const int lk  = (l >> 4) * 8;
    const int lk4 = (l >> 4) * 4;

    // staging map: one 8-elem chunk of x and h per thread per K-step
    const int arow = tid >> 2;        // 0..63
    const int ach  = (tid & 3) * 8;   // 0,8,16,24
    const bool am  = (rst[m0 + arow] != 0);

    f32x4 acc[8][2];
    #pragma unroll
    for (int g = 0; g < 8; ++g)
        #pragma unroll
        for (int fm = 0; fm < 2; ++fm)
            acc[g][fm] = (f32x4){0.f, 0.f, 0.f, 0.f};

    for (int k0 = 0; k0 < 512; k0 += 32) {
        __syncthreads();
        // ---- stage x / h (f32 -> split f16) ----
        {
            const float* xp = x    + (size_t)(m0 + arow) * 512 + k0 + ach;
            const float* hp = hsrc + (size_t)(m0 + arow) * 512 + k0 + ach;
            float4 x0 = *(const float4*)xp, x1 = *(const float4*)(xp + 4);
            float4 h0 = *(const float4*)hp, h1 = *(const float4*)(hp + 4);
            if (am) { h0 = make_float4(0, 0, 0, 0); h1 = make_float4(0, 0, 0, 0); }
            float xf[8] = {x0.x, x0.y, x0.z, x0.w, x1.x, x1.y, x1.z, x1.w};
            float hf[8] = {h0.x, h0.y, h0.z, h0.w, h1.x, h1.y, h1.z, h1.w};
            f16x8 xh8, xl8, hh8, hl8;
            #pragma unroll
            for (int j = 0; j < 8; ++j) {
                float v = xf[j];
                _Float16 th = (_Float16)v;
                xh8[j] = th; xl8[j] = (_Float16)((v - (float)th) * 2048.0f);
                v = hf[j];
                th = (_Float16)v;
                hh8[j] = th; hl8[j] = (_Float16)((v - (float)th) * 2048.0f);
            }
            *(f16x8*)&A[0][arow * 40 + ach] = xh8;
            *(f16x8*)&A[1][arow * 40 + ach] = xl8;
            *(f16x8*)&A[2][arow * 40 + ach] = hh8;
            *(f16x8*)&A[3][arow * 40 + ach] = hl8;
        }
        // ---- stage weight strips (already split) ----
        #pragma unroll
        for (int c = 0; c < 6; ++c) {
            int idx = tid + c * 256;
            int p   = idx >> 7;           // plane 0..11
            int row = (idx >> 2) & 31;
            int ch  = (idx & 3) * 8;
            int s   = p >> 1;
            const _Float16* src = (p & 1) ? WT_lo : WT_hi;
            int nb = (s < 3 ? s * 512 : 1536 + (s - 3) * 512) + c0 + row;
            f16x8 v = *(const f16x8*)(src + (size_t)nb * 512 + k0 + ch);
            *(f16x8*)&Bs[p][row * 40 + ch] = v;
        }
        __syncthreads();

        // ---- fragments + MFMA ----
        f16x8 bx[12];
        #pragma unroll
        for (int p = 0; p < 12; ++p)
            bx[p] = *(const f16x8*)&Bs[p][(wn * 16 + lr) * 40 + lk];

        #pragma unroll
        for (int fm = 0; fm < 2; ++fm) {
            const int ar = (wm * 32 + fm * 16 + lr) * 40 + lk;
            f16x8 xh = *(const f16x8*)&A[0][ar];
            f16x8 xl = *(const f16x8*)&A[1][ar];
            f16x8 hh = *(const f16x8*)&A[2][ar];
            f16x8 hl = *(const f16x8*)&A[3][ar];
            // r: strips 0 (Wi_r) + 3 (Wh_r)
            acc[0][fm] = MFMA16(xh, bx[0],  acc[0][fm]);
            acc[0][fm] = MFMA16(hh, bx[6],  acc[0][fm]);
            acc[4][fm] = MFMA16(xh, bx[1],  acc[4][fm]);
            acc[4][fm] = MFMA16(xl, bx[0],  acc[4][fm]);
            acc[4][fm] = MFMA16(hh, bx[7],  acc[4][fm]);
            acc[4][fm] = MFMA16(hl, bx[6],  acc[4][fm]);
            // z: strips 1 + 4
            acc[1][fm] = MFMA16(xh, bx[2],  acc[1][fm]);
            acc[1][fm] = MFMA16(hh, bx[8],  acc[1][fm]);
            acc[5][fm] = MFMA16(xh, bx[3],  acc[5][fm]);
            acc[5][fm] = MFMA16(xl, bx[2],  acc[5][fm]);
            acc[5][fm] = MFMA16(hh, bx[9],  acc[5][fm]);
            acc[5][fm] = MFMA16(hl, bx[8],  acc[5][fm]);
            // gn: strip 2 (x only)
            acc[2][fm] = MFMA16(xh, bx[4],  acc[2][fm]);
            acc[6][fm] = MFMA16(xh, bx[5],  acc[6][fm]);
            acc[6][fm] = MFMA16(xl, bx[4],  acc[6][fm]);
            // hn: strip 5 (h only)
            acc[3][fm] = MFMA16(hh, bx[10], acc[3][fm]);
            acc[7][fm] = MFMA16(hh, bx[11], acc[7][fm]);
            acc[7][fm] = MFMA16(hl, bx[10], acc[7][fm]);
        }
    }

    // ---- epilogue: gates ----
    const int j = c0 + wn * 16 + lr;
    const float biR = bi[j], biZ = bi[512 + j], biN = bi[1024 + j], bhn = bh_n[j];
    const float s = 1.0f / 2048.0f;
    #pragma unroll
    for (int fm = 0; fm < 2; ++fm) {
        #pragma unroll
        for (int i = 0; i < 4; ++i) {
            int row = m0 + wm * 32 + fm * 16 + lk4 + i;
            bool rm = (rst[row] != 0);
            float heff = rm ? 0.f : hsrc[(size_t)row * 512 + j];
            float aR = acc[0][fm][i] + acc[4][fm][i] * s;
            float aZ = acc[1][fm][i] + acc[5][fm][i] * s;
            float aG = acc[2][fm][i] + acc[6][fm][i] * s;
            float aH = acc[3][fm][i] + acc[7][fm][i] * s;
            float rg = sigf_(aR + biR);
            float zg = sigf_(aZ + biZ);
            float ng = tanhf_(aG + biN + rg * (aH + bhn));
            float hv = (1.f - zg) * ng + zg * heff;
            hdst[(size_t)row * 512 + j] = hv;
            if (hT_out) hT_out[(size_t)row * 512 + j] = hv;
        }
    }
}

// ---------------------------------------------------------------------------
// Fallback (round-1 f32 kernel) if ws is too small for split weights.
// ---------------------------------------------------------------------------
constexpr int BM = 32, BN = 32, BK_F = 32;
constexpr int LDT = BM + 4;

__global__ __launch_bounds__(256, 1) void gru_step_f32(
    const float* __restrict__ x, const int* __restrict__ rst,
    const float* __restrict__ h_prev, const float* __restrict__ Wi,
    const float* __restrict__ bi, const float* __restrict__ Wh_rz,
    const float* __restrict__ Wh_n, const float* __restrict__ bh_n,
    float* __restrict__ h_out, float* __restrict__ hT_out)
{
    __shared__ float xs[BK_F][LDT];
    __shared__ float hs[BK_F][LDT];
    __shared__ float wt[6][BK_F][LDT];

    const int tid = threadIdx.x;
    const int bm0 = blockIdx.x * BM;
    const int jn0 = blockIdx.y * BN;
    const int lr = tid >> 3;
    const int lc = (tid & 7) << 2;
    const int ty = tid >> 4, tx = tid & 15;
    const int row0 = 2 * ty, col0 = 2 * tx;

    float aR[2][2] = {{0,0},{0,0}}, aZ[2][2] = {{0,0},{0,0}}, aN[2][2] = {{0,0},{0,0}};
    float hR[2][2] = {{0,0},{0,0}}, hZ[2][2] = {{0,0},{0,0}}, hN[2][2] = {{0,0},{0,0}};

    const int ldrow = bm0 + lr;
    const bool rmaskld = (rst[ldrow] != 0);
    const float* xrow = x + (size_t)ldrow * 512;
    const float* hrow = h_prev + (size_t)ldrow * 512;

    for (int k0 = 0; k0 < 512; k0 += BK_F) {
        float4 xv = *(const float4*)(xrow + k0 + lc);
        float4 hv = *(const float4*)(hrow + k0 + lc);
        if (rmaskld) { hv.x = hv.y = hv.z = hv.w = 0.f; }
        const float* wi_row = Wi + (size_t)(k0 + lr) * 1536;
        const float* wh_row = Wh_rz + (size_t)(k0 + lr) * 1024;
        float4 w0v = *(const float4*)(wi_row + jn0 + lc);
        float4 w1v = *(const float4*)(wi_row + 512 + jn0 + lc);
        float4 w2v = *(const float4*)(wi_row + 1024 + jn0 + lc);
        float4 w3v = *(const float4*)(wh_row + jn0 + lc);
        float4 w4v = *(const float4*)(wh_row + 512 + jn0 + lc);
        float4 w5v = *(const float4*)(Wh_n + (size_t)(k0 + lr) * 512 + jn0 + lc);
        __syncthreads();
        xs[lc+0][lr]=xv.x; xs[lc+1][lr]=xv.y; xs[lc+2][lr]=xv.z; xs[lc+3][lr]=xv.w;
        hs[lc+0][lr]=hv.x; hs[lc+1][lr]=hv.y; hs[lc+2][lr]=hv.z; hs[lc+3][lr]=hv.w;
        *(float4*)&wt[0][lr][lc] = w0v; *(float4*)&wt[1][lr][lc] = w1v;
        *(float4*)&wt[2][lr][lc] = w2v; *(float4*)&wt[3][lr][lc] = w3v;
        *(float4*)&wt[4][lr][lc] = w4v; *(float4*)&wt[5][lr][lc] = w5v;
        __syncthreads();
        #pragma unroll
        for (int kk = 0; kk < BK_F; ++kk) {
            float2 xa = *(const float2*)&xs[kk][row0];
            float2 ha = *(const float2*)&hs[kk][row0];
            float2 w0 = *(const float2*)&wt[0][kk][col0];
            float2 w1 = *(const float2*)&wt[1][kk][col0];
            float2 w2 = *(const float2*)&wt[2][kk][col0];
            float2 w3 = *(const float2*)&wt[3][kk][col0];
            float2 w4 = *(const float2*)&wt[4][kk][col0];
            float2 w5 = *(const float2*)&wt[5][kk][col0];
            aR[0][0]=fmaf(xa.x,w0.x,aR[0][0]); aR[0][1]=fmaf(xa.x,w0.y,aR[0][1]);
            aR[1][0]=fmaf(xa.y,w0.x,aR[1][0]); aR[1][1]=fmaf(xa.y,w0.y,aR[1][1]);
            aZ[0][0]=fmaf(xa.x,w1.x,aZ[0][0]); aZ[0][1]=fmaf(xa.x,w1.y,aZ[0][1]);
            aZ[1][0]=fmaf(xa.y,w1.x,aZ[1][0]); aZ[1][1]=fmaf(xa.y,w1.y,aZ[1][1]);
            aN[0][0]=fmaf(xa.x,w2.x,aN[0][0]); aN[0][1]=fmaf(xa.x,w2.y,aN[0][1]);
            aN[1][0]=fmaf(xa.y,w2.x,aN[1][0]); aN[1][1]=fmaf(xa.y,w2.y,aN[1][1]);
            hR[0][0]=fmaf(ha.x,w3.x,hR[0][0]); hR[0][1]=fmaf(ha.x,w3.y,hR[0][1]);
            hR[1][0]=fmaf(ha.y,w3.x,hR[1][0]); hR[1][1]=fmaf(ha.y,w3.y,hR[1][1]);
            hZ[0][0]=fmaf(ha.x,w4.x,hZ[0][0]); hZ[0][1]=fmaf(ha.x,w4.y,hZ[0][1]);
            hZ[1][0]=fmaf(ha.y,w4.x,hZ[1][0]); hZ[1][1]=fmaf(ha.y,w4.y,hZ[1][1]);
            hN[0][0]=fmaf(ha.x,w5.x,hN[0][0]); hN[0][1]=fmaf(ha.x,w5.y,hN[0][1]);
            hN[1][0]=fmaf(ha.y,w5.x,hN[1][0]); hN[1][1]=fmaf(ha.y,w5.y,hN[1][1]);
        }
    }
    #pragma unroll
    for (int ii = 0; ii < 2; ++ii) {
        const int b = bm0 + row0 + ii;
        const bool rm = (rst[b] != 0);
        #pragma unroll
        for (int jj = 0; jj < 2; ++jj) {
            const int jn = jn0 + col0 + jj;
            const float heff = rm ? 0.f : h_prev[(size_t)b * 512 + jn];
            const float r = sigf_(aR[ii][jj] + bi[jn] + hR[ii][jj]);
            const float z = sigf_(aZ[ii][jj] + bi[512 + jn] + hZ[ii][jj]);
            const float n = tanhf(aN[ii][jj] + bi[1024 + jn] + r * (hN[ii][jj] + bh_n[jn]));
            const float v = (1.f - z) * n + z * heff;
            h_out[(size_t)b * 512 + jn] = v;
            if (hT_out) hT_out[(size_t)b * 512 + jn] = v;
        }
    }
}

// ---------------------------------------------------------------------------
extern "C" void kernel_launch(void* const* d_in, const int* in_sizes, int n_in,
                              void* d_out, int out_size, void* d_ws, size_t ws_size,
                              hipStream_t stream) {
    const float* h0     = (const float*)d_in[0];
    const float* ins    = (const float*)d_in[1];
    const int*   resets = (const int*)  d_in[2];
    const float* Wi     = (const float*)d_in[3];
    const float* bi     = (const float*)d_in[4];
    const float* Wh_rz  = (const float*)d_in[5];
    const float* Wh_n   = (const float*)d_in[6];
    const float* bh_n   = (const float*)d_in[7];

    float* out = (float*)d_out;
    float* hT  = out;
    float* ys  = out + (size_t)B_SZ * HD;

    const size_t WPLANE = (size_t)3072 * 512;       // elements per plane
    const size_t WS_NEED = WPLANE * 2 * sizeof(_Float16);

    if (ws_size >= WS_NEED) {
        _Float16* WT_hi = (_Float16*)d_ws;
        _Float16* WT_lo = WT_hi + WPLANE;
        conv_w<<<dim3(8, 48), 256, 0, stream>>>(Wi, Wh_rz, Wh_n, WT_hi, WT_lo);
        for (int t = 0; t < T_STEPS; ++t) {
            const float* hp = (t == 0) ? h0 : (ys + (size_t)(t - 1) * B_SZ * HD);
            float* ho = ys + (size_t)t * B_SZ * HD;
            gru_fused<<<dim3(16, 8), 256, 0, stream>>>(
                ins + (size_t)t * B_SZ * HD, resets + (size_t)t * B_SZ,
                hp, WT_hi, WT_lo, bi, bh_n,
                ho, (t == T_STEPS - 1) ? hT : nullptr);
        }
    } else {
        dim3 grid(B_SZ / BM, HD / BN);
        for (int t = 0; t < T_STEPS; ++t) {
            const float* hp = (t == 0) ? h0 : (ys + (size_t)(t - 1) * B_SZ * HD);
            float* ho = ys + (size_t)t * B_SZ * HD;
            gru_step_f32<<<grid, 256, 0, stream>>>(
                ins + (size_t)t * B_SZ * HD, resets + (size_t)t * B_SZ,
                hp, Wi, bi, Wh_rz, Wh_n, bh_n,
                ho, (t == T_STEPS - 1) ? hT : nullptr);
        }
    }
}

// Round 3
// 2392.900 us; speedup vs baseline: 3.1978x; 1.4842x over previous
//
#include <hip/hip_runtime.h>
#include <cmath>

// GRU scan, T=128 B=512 D=H=512, split-f16 MFMA (f32-accurate):
//   v = hi + lo/2048 ; a*b ~= ah*bh + (ah*bl + al*bh)/2048
// Phase 0: transpose+split all weights -> WT_hi/WT_lo [3072][512] (d_ws).
// Phase 1 (parallel): gi = x@Wi + bi for CH steps at a time (big GEMM, d_ws).
// Phase 2 (sequential): per-step kernel computes h@[Wh_r|Wh_z|Wh_n] + gates.
// d_out = [hT (B*H) | ys (T*B*H)]; h_prev for step t read from ys[t-1].

#define T_STEPS 128
#define B_SZ 512
#define HD 512

typedef __attribute__((ext_vector_type(8))) _Float16 f16x8;
typedef __attribute__((ext_vector_type(4))) float f32x4;

#define MFMA16(a, b, c) __builtin_amdgcn_mfma_f32_16x16x32_f16((a), (b), (c), 0, 0, 0)

__device__ __forceinline__ float sigf_(float x) { return 1.0f / (1.0f + __expf(-x)); }
__device__ __forceinline__ float tanhf_(float x) { return 1.0f - 2.0f / (__expf(2.0f * x) + 1.0f); }

// ---------------------------------------------------------------------------
// Phase 0: transpose + split weights. WT[n][k], n<1536: Wi col n;
// n>=1536: m=n-1536, g=m>>9, c=m&511: g<2 -> Wh_rz[k][g*512+c]; g==2 -> Wh_n[k][c]
// ---------------------------------------------------------------------------
__global__ __launch_bounds__(256) void conv_w(
    const float* __restrict__ Wi, const float* __restrict__ Wh_rz,
    const float* __restrict__ Wh_n,
    _Float16* __restrict__ WT_hi, _Float16* __restrict__ WT_lo)
{
    __shared__ float Tl[64][65];
    const int tid = threadIdx.x;
    const int k0 = blockIdx.x * 64;
    const int n0 = blockIdx.y * 64;

    const float* base;
    int stride;
    if (n0 < 1536) { base = Wi + n0; stride = 1536; }
    else {
        int m = n0 - 1536, g = m >> 9, c = m & 511;
        if (g < 2) { base = Wh_rz + g * 512 + c; stride = 1024; }
        else       { base = Wh_n + c;            stride = 512; }
    }

    #pragma unroll
    for (int p = 0; p < 4; ++p) {
        int kr = p * 16 + (tid >> 4);
        int nc = (tid & 15) * 4;
        float4 v = *(const float4*)(base + (size_t)(k0 + kr) * stride + nc);
        Tl[kr][nc + 0] = v.x; Tl[kr][nc + 1] = v.y;
        Tl[kr][nc + 2] = v.z; Tl[kr][nc + 3] = v.w;
    }
    __syncthreads();

    const int nr  = tid >> 2;
    const int kc0 = (tid & 3) * 16;
    f16x8 h0v, h1v, l0v, l1v;
    #pragma unroll
    for (int j = 0; j < 16; ++j) {
        float v = Tl[kc0 + j][nr];
        _Float16 th = (_Float16)v;
        _Float16 tl = (_Float16)((v - (float)th) * 2048.0f);
        if (j < 8) { h0v[j] = th; l0v[j] = tl; }
        else       { h1v[j - 8] = th; l1v[j - 8] = tl; }
    }
    size_t o = (size_t)(n0 + nr) * 512 + k0 + kc0;
    *(f16x8*)(WT_hi + o)     = h0v;
    *(f16x8*)(WT_hi + o + 8) = h1v;
    *(f16x8*)(WT_lo + o)     = l0v;
    *(f16x8*)(WT_lo + o + 8) = l1v;
}

// ---------------------------------------------------------------------------
// Phase 1: gi = x @ Wi + bi   (rows R = CH*512, cols 1536, K=512)
// BM=128, BN=64, BK=32, block 256 = 4 waves, wave w owns rows w*32..w*32+31,
// all 64 cols. Register prefetch of next K-stage.
// ---------------------------------------------------------------------------
__global__ __launch_bounds__(256, 1) void gi_gemm(
    const float* __restrict__ x,        // [R][512]
    const _Float16* __restrict__ WT_hi, // rows 0..1535 = Wi cols
    const _Float16* __restrict__ WT_lo,
    const float* __restrict__ bi,       // [1536]
    float* __restrict__ gi)             // [R][1536]
{
    __shared__ _Float16 Ah[128 * 40], Al[128 * 40];
    __shared__ _Float16 Bh[64 * 40],  Bl[64 * 40];

    const int tid = threadIdx.x;
    const int m0 = blockIdx.x * 128;
    const int n0 = blockIdx.y * 64;
    const int l = tid & 63, w = tid >> 6;
    const int lr = l & 15, lk = (l >> 4) * 8;

    const int ar = tid >> 1;        // 0..127
    const int ac = (tid & 1) * 16;  // 0 / 16
    const int br = tid >> 2;        // 0..63
    const int bc = (tid & 3) * 8;

    const float*    xrow = x + (size_t)(m0 + ar) * 512 + ac;
    const _Float16* bhp  = WT_hi + (size_t)(n0 + br) * 512 + bc;
    const _Float16* blp  = WT_lo + (size_t)(n0 + br) * 512 + bc;

    f32x4 am_[2][4], ac_[2][4];
    #pragma unroll
    for (int i = 0; i < 2; ++i)
        #pragma unroll
        for (int jq = 0; jq < 4; ++jq) {
            am_[i][jq] = (f32x4){0, 0, 0, 0};
            ac_[i][jq] = (f32x4){0, 0, 0, 0};
        }

    float4 xv0 = *(const float4*)(xrow + 0);
    float4 xv1 = *(const float4*)(xrow + 4);
    float4 xv2 = *(const float4*)(xrow + 8);
    float4 xv3 = *(const float4*)(xrow + 12);
    f16x8 bhv = *(const f16x8*)bhp;
    f16x8 blv = *(const f16x8*)blp;

    for (int s = 0; s < 16; ++s) {
        __syncthreads();
        {   // write A (16 f32 -> 2x f16x8 per plane)
            float xf[16] = {xv0.x, xv0.y, xv0.z, xv0.w, xv1.x, xv1.y, xv1.z, xv1.w,
                            xv2.x, xv2.y, xv2.z, xv2.w, xv3.x, xv3.y, xv3.z, xv3.w};
            f16x8 hh0, hl0, hh1, hl1;
            #pragma unroll
            for (int j = 0; j < 8; ++j) {
                float v = xf[j];
                _Float16 th = (_Float16)v;
                hh0[j] = th; hl0[j] = (_Float16)((v - (float)th) * 2048.0f);
                v = xf[j + 8];
                th = (_Float16)v;
                hh1[j] = th; hl1[j] = (_Float16)((v - (float)th) * 2048.0f);
            }
            *(f16x8*)&Ah[ar * 40 + ac]     = hh0;
            *(f16x8*)&Al[ar * 40 + ac]     = hl0;
            *(f16x8*)&Ah[ar * 40 + ac + 8] = hh1;
            *(f16x8*)&Al[ar * 40 + ac + 8] = hl1;
            *(f16x8*)&Bh[br * 40 + bc] = bhv;
            *(f16x8*)&Bl[br * 40 + bc] = blv;
        }
        __syncthreads();
        if (s < 15) {
            const int k0 = (s + 1) * 32;
            xv0 = *(const float4*)(xrow + k0 + 0);
            xv1 = *(const float4*)(xrow + k0 + 4);
            xv2 = *(const float4*)(xrow + k0 + 8);
            xv3 = *(const float4*)(xrow + k0 + 12);
            bhv = *(const f16x8*)(bhp + k0);
            blv = *(const f16x8*)(blp + k0);
        }
        f16x8 ah[2], al[2], bhf[4], blf[4];
        #pragma unroll
        for (int fm = 0; fm < 2; ++fm) {
            ah[fm] = *(const f16x8*)&Ah[(w * 32 + fm * 16 + lr) * 40 + lk];
            al[fm] = *(const f16x8*)&Al[(w * 32 + fm * 16 + lr) * 40 + lk];
        }
        #pragma unroll
        for (int fn = 0; fn < 4; ++fn) {
            bhf[fn] = *(const f16x8*)&Bh[(fn * 16 + lr) * 40 + lk];
            blf[fn] = *(const f16x8*)&Bl[(fn * 16 + lr) * 40 + lk];
        }
        #pragma unroll
        for (int fm = 0; fm < 2; ++fm)
            #pragma unroll
            for (int fn = 0; fn < 4; ++fn) {
                am_[fm][fn] = MFMA16(ah[fm], bhf[fn], am_[fm][fn]);
                ac_[fm][fn] = MFMA16(ah[fm], blf[fn], ac_[fm][fn]);
                ac_[fm][fn] = MFMA16(al[fm], bhf[fn], ac_[fm][fn]);
            }
    }

    const float inv = 1.0f / 2048.0f;
    #pragma unroll
    for (int fm = 0; fm < 2; ++fm)
        #pragma unroll
        for (int fn = 0; fn < 4; ++fn) {
            const int col = n0 + fn * 16 + lr;
            const float bv = bi[col];
            #pragma unroll
            for (int i = 0; i < 4; ++i) {
                int row = m0 + w * 32 + fm * 16 + (l >> 4) * 4 + i;
                gi[(size_t)row * 1536 + col] =
                    am_[fm][fn][i] + ac_[fm][fn][i] * inv + bv;
            }
        }
}

// ---------------------------------------------------------------------------
// Phase 2: sequential step. acc = h_eff @ [Wh_r|Wh_z|Wh_n] (32x32 tile, BK=64)
// grid (16 j-tiles, 16 m-tiles) = 256 blocks, 4 waves: rh=w>>1 rows, jh=w&1 cols.
// Register prefetch of next stage's h + weight chunks.
// ---------------------------------------------------------------------------
__global__ __launch_bounds__(256, 1) void gru_step_h(
    const int*   __restrict__ rst,      // [B]
    const float* __restrict__ hsrc,     // [B][512]
    const _Float16* __restrict__ WT_hi, // hidden rows at 1536+
    const _Float16* __restrict__ WT_lo,
    const float* __restrict__ gi_t,     // [512][1536] (bi folded in)
    const float* __restrict__ bh_n,     // [512]
    float* __restrict__ hdst,
    float* __restrict__ hT_out)
{
    __shared__ _Float16 Ah[32 * 72], Al[32 * 72];
    __shared__ _Float16 Bs[6][32 * 72];

    const int tid = threadIdx.x;
    const int j0 = blockIdx.x * 32;
    const int m0 = blockIdx.y * 32;
    const int l = tid & 63, w = tid >> 6;
    const int rh = w >> 1, jh = w & 1;
    const int lr = l & 15, lk = (l >> 4) * 8;

    const int arow = tid >> 3;       // 0..31
    const int ach  = (tid & 7) * 8;  // 0..56
    const bool am  = (rst[m0 + arow] != 0);
    const float* hrow = hsrc + (size_t)(m0 + arow) * 512 + ach;

    const _Float16* bp[6];
    #pragma unroll
    for (int c = 0; c < 6; ++c) {
        const int sgrp = c >> 1;
        const _Float16* src = (c & 1) ? WT_lo : WT_hi;
        bp[c] = src + (size_t)(1536 + sgrp * 512 + j0 + arow) * 512 + ach;
    }

    f32x4 aRm = {0,0,0,0}, aRc = {0,0,0,0};
    f32x4 aZm = {0,0,0,0}, aZc = {0,0,0,0};
    f32x4 aNm = {0,0,0,0}, aNc = {0,0,0,0};

    float4 a0 = *(const float4*)(hrow);
    float4 a1 = *(const float4*)(hrow + 4);
    f16x8 wv0 = *(const f16x8*)bp[0];
    f16x8 wv1 = *(const f16x8*)bp[1];
    f16x8 wv2 = *(const f16x8*)bp[2];
    f16x8 wv3 = *(const f16x8*)bp[3];
    f16x8 wv4 = *(const f16x8*)bp[4];
    f16x8 wv5 = *(const f16x8*)bp[5];

    for (int s = 0; s < 8; ++s) {
        __syncthreads();
        {
            float xf[8] = {a0.x, a0.y, a0.z, a0.w, a1.x, a1.y, a1.z, a1.w};
            f16x8 hh, hl;
            #pragma unroll
            for (int j = 0; j < 8; ++j) {
                float v = am ? 0.0f : xf[j];
                _Float16 th = (_Float16)v;
                hh[j] = th; hl[j] = (_Float16)((v - (float)th) * 2048.0f);
            }
            *(f16x8*)&Ah[arow * 72 + ach] = hh;
            *(f16x8*)&Al[arow * 72 + ach] = hl;
            *(f16x8*)&Bs[0][arow * 72 + ach] = wv0;
            *(f16x8*)&Bs[1][arow * 72 + ach] = wv1;
            *(f16x8*)&Bs[2][arow * 72 + ach] = wv2;
            *(f16x8*)&Bs[3][arow * 72 + ach] = wv3;
            *(f16x8*)&Bs[4][arow * 72 + ach] = wv4;
            *(f16x8*)&Bs[5][arow * 72 + ach] = wv5;
        }
        __syncthreads();
        if (s < 7) {
            const int k0 = (s + 1) * 64;
            a0 = *(const float4*)(hrow + k0);
            a1 = *(const float4*)(hrow + k0 + 4);
            wv0 = *(const f16x8*)(bp[0] + k0);
            wv1 = *(const f16x8*)(bp[1] + k0);
            wv2 = *(const f16x8*)(bp[2] + k0);
            wv3 = *(const f16x8*)(bp[3] + k0);
            wv4 = *(const f16x8*)(bp[4] + k0);
            wv5 = *(const f16x8*)(bp[5] + k0);
        }
        #pragma unroll
        for (int kk = 0; kk < 2; ++kk) {
            const int ko = kk * 32 + lk;
            f16x8 ahf = *(const f16x8*)&Ah[(rh * 16 + lr) * 72 + ko];
            f16x8 alf = *(const f16x8*)&Al[(rh * 16 + lr) * 72 + ko];
            f16x8 b0 = *(const f16x8*)&Bs[0][(jh * 16 + lr) * 72 + ko];
            f16x8 b1 = *(const f16x8*)&Bs[1][(jh * 16 + lr) * 72 + ko];
            f16x8 b2 = *(const f16x8*)&Bs[2][(jh * 16 + lr) * 72 + ko];
            f16x8 b3 = *(const f16x8*)&Bs[3][(jh * 16 + lr) * 72 + ko];
            f16x8 b4 = *(const f16x8*)&Bs[4][(jh * 16 + lr) * 72 + ko];
            f16x8 b5 = *(const f16x8*)&Bs[5][(jh * 16 + lr) * 72 + ko];
            aRm = MFMA16(ahf, b0, aRm);
            aRc = MFMA16(ahf, b1, aRc);
            aRc = MFMA16(alf, b0, aRc);
            aZm = MFMA16(ahf, b2, aZm);
            aZc = MFMA16(ahf, b3, aZc);
            aZc = MFMA16(alf, b2, aZc);
            aNm = MFMA16(ahf, b4, aNm);
            aNc = MFMA16(ahf, b5, aNc);
            aNc = MFMA16(alf, b4, aNc);
        }
    }

    const int j = j0 + jh * 16 + lr;
    const float bhn = bh_n[j];
    const float inv = 1.0f / 2048.0f;
    const int rowbase = m0 + rh * 16 + (l >> 4) * 4;
    #pragma unroll
    for (int i = 0; i < 4; ++i) {
        const int row = rowbase + i;
        const bool rm = (rst[row] != 0);
        const float heff = rm ? 0.f : hsrc[(size_t)row * 512 + j];
        const float R = aRm[i] + aRc[i] * inv;
        const float Z = aZm[i] + aZc[i] * inv;
        const float N = aNm[i] + aNc[i] * inv;
        const size_t gb = (size_t)row * 1536 + j;
        const float r = sigf_(gi_t[gb] + R);
        const float z = sigf_(gi_t[gb + 512] + Z);
        const float n = tanhf_(gi_t[gb + 1024] + r * (N + bhn));
        const float hv = (1.f - z) * n + z * heff;
        hdst[(size_t)row * 512 + j] = hv;
        if (hT_out) hT_out[(size_t)row * 512 + j] = hv;
    }
}

// ---------------------------------------------------------------------------
// Fallback A (round-2 fused, needs only weight ws) and B (pure f32).
// ---------------------------------------------------------------------------
__global__ __launch_bounds__(256, 1) void gru_fused(
    const float* __restrict__ x, const int* __restrict__ rst,
    const float* __restrict__ hsrc,
    const _Float16* __restrict__ WT_hi, const _Float16* __restrict__ WT_lo,
    const float* __restrict__ bi, const float* __restrict__ bh_n,
    float* __restrict__ hdst, float* __restrict__ hT_out)
{
    __shared__ _Float16 A[4][64 * 40];
    __shared__ _Float16 Bs[12][32 * 40];

    const int tid = threadIdx.x;
    const int c0 = blockIdx.x * 32;
    const int m0 = blockIdx.y * 64;
    const int l  = tid & 63;
    const int w  = tid >> 6;
    const int wm = w >> 1, wn = w & 1;
    const int lr  = l & 15;
    const int lk  = (l >> 4) * 8;
    const int lk4 = (l >> 4) * 4;

    const int arow = tid >> 2;
    const int ach  = (tid & 3) * 8;
    const bool am  = (rst[m0 + arow] != 0);

    f32x4 acc[8][2];
    #pragma unroll
    for (int g = 0; g < 8; ++g)
        #pragma unroll
        for (int fm = 0; fm < 2; ++fm)
            acc[g][fm] = (f32x4){0.f, 0.f, 0.f, 0.f};

    for (int k0 = 0; k0 < 512; k0 += 32) {
        __syncthreads();
        {
            const float* xp = x    + (size_t)(m0 + arow) * 512 + k0 + ach;
            const float* hp = hsrc + (size_t)(m0 + arow) * 512 + k0 + ach;
            float4 x0 = *(const float4*)xp, x1 = *(const float4*)(xp + 4);
            float4 h0v = *(const float4*)hp, h1v = *(const float4*)(hp + 4);
            if (am) { h0v = make_float4(0,0,0,0); h1v = make_float4(0,0,0,0); }
            float xf[8] = {x0.x,x0.y,x0.z,x0.w,x1.x,x1.y,x1.z,x1.w};
            float hf[8] = {h0v.x,h0v.y,h0v.z,h0v.w,h1v.x,h1v.y,h1v.z,h1v.w};
            f16x8 xh8, xl8, hh8, hl8;
            #pragma unroll
            for (int jq = 0; jq < 8; ++jq) {
                float v = xf[jq];
                _Float16 th = (_Float16)v;
                xh8[jq] = th; xl8[jq] = (_Float16)((v - (float)th) * 2048.0f);
                v = hf[jq];
                th = (_Float16)v;
                hh8[jq] = th; hl8[jq] = (_Float16)((v - (float)th) * 2048.0f);
            }
            *(f16x8*)&A[0][arow * 40 + ach] = xh8;
            *(f16x8*)&A[1][arow * 40 + ach] = xl8;
            *(f16x8*)&A[2][arow * 40 + ach] = hh8;
            *(f16x8*)&A[3][arow * 40 + ach] = hl8;
        }
        #pragma unroll
        for (int c = 0; c < 6; ++c) {
            int idx = tid + c * 256;
            int p   = idx >> 7;
            int row = (idx >> 2) & 31;
            int ch  = (idx & 3) * 8;
            int sgrp = p >> 1;
            const _Float16* src = (p & 1) ? WT_lo : WT_hi;
            int nb = (sgrp < 3 ? sgrp * 512 : 1536 + (sgrp - 3) * 512) + c0 + row;
            f16x8 v = *(const f16x8*)(src + (size_t)nb * 512 + k0 + ch);
            *(f16x8*)&Bs[p][row * 40 + ch] = v;
        }
        __syncthreads();

        f16x8 bx[12];
        #pragma unroll
        for (int p = 0; p < 12; ++p)
            bx[p] = *(const f16x8*)&Bs[p][(wn * 16 + lr) * 40 + lk];

        #pragma unroll
        for (int fm = 0; fm < 2; ++fm) {
            const int arx = (wm * 32 + fm * 16 + lr) * 40 + lk;
            f16x8 xh = *(const f16x8*)&A[0][arx];
            f16x8 xl = *(const f16x8*)&A[1][arx];
            f16x8 hh = *(const f16x8*)&A[2][arx];
            f16x8 hl = *(const f16x8*)&A[3][arx];
            acc[0][fm] = MFMA16(xh, bx[0],  acc[0][fm]);
            acc[0][fm] = MFMA16(hh, bx[6],  acc[0][fm]);
            acc[4][fm] = MFMA16(xh, bx[1],  acc[4][fm]);
            acc[4][fm] = MFMA16(xl, bx[0],  acc[4][fm]);
            acc[4][fm] = MFMA16(hh, bx[7],  acc[4][fm]);
            acc[4][fm] = MFMA16(hl, bx[6],  acc[4][fm]);
            acc[1][fm] = MFMA16(xh, bx[2],  acc[1][fm]);
            acc[1][fm] = MFMA16(hh, bx[8],  acc[1][fm]);
            acc[5][fm] = MFMA16(xh, bx[3],  acc[5][fm]);
            acc[5][fm] = MFMA16(xl, bx[2],  acc[5][fm]);
            acc[5][fm] = MFMA16(hh, bx[9],  acc[5][fm]);
            acc[5][fm] = MFMA16(hl, bx[8],  acc[5][fm]);
            acc[2][fm] = MFMA16(xh, bx[4],  acc[2][fm]);
            acc[6][fm] = MFMA16(xh, bx[5],  acc[6][fm]);
            acc[6][fm] = MFMA16(xl, bx[4],  acc[6][fm]);
            acc[3][fm] = MFMA16(hh, bx[10], acc[3][fm]);
            acc[7][fm] = MFMA16(hh, bx[11], acc[7][fm]);
            acc[7][fm] = MFMA16(hl, bx[10], acc[7][fm]);
        }
    }

    const int j = c0 + wn * 16 + lr;
    const float biR = bi[j], biZ = bi[512 + j], biN = bi[1024 + j], bhn = bh_n[j];
    const float sc = 1.0f / 2048.0f;
    #pragma unroll
    for (int fm = 0; fm < 2; ++fm) {
        #pragma unroll
        for (int i = 0; i < 4; ++i) {
            int row = m0 + wm * 32 + fm * 16 + lk4 + i;
            bool rm = (rst[row] != 0);
            float heff = rm ? 0.f : hsrc[(size_t)row * 512 + j];
            float aR = acc[0][fm][i] + acc[4][fm][i] * sc;
            float aZ = acc[1][fm][i] + acc[5][fm][i] * sc;
            float aG = acc[2][fm][i] + acc[6][fm][i] * sc;
            float aH = acc[3][fm][i] + acc[7][fm][i] * sc;
            float rg = sigf_(aR + biR);
            float zg = sigf_(aZ + biZ);
            float ng = tanhf_(aG + biN + rg * (aH + bhn));
            float hv = (1.f - zg) * ng + zg * heff;
            hdst[(size_t)row * 512 + j] = hv;
            if (hT_out) hT_out[(size_t)row * 512 + j] = hv;
        }
    }
}

constexpr int BM_F = 32, BN_F = 32, BK_F = 32;
constexpr int LDT = BM_F + 4;

__global__ __launch_bounds__(256, 1) void gru_step_f32(
    const float* __restrict__ x, const int* __restrict__ rst,
    const float* __restrict__ h_prev, const float* __restrict__ Wi,
    const float* __restrict__ bi, const float* __restrict__ Wh_rz,
    const float* __restrict__ Wh_n, const float* __restrict__ bh_n,
    float* __restrict__ h_out, float* __restrict__ hT_out)
{
    __shared__ float xs[BK_F][LDT];
    __shared__ float hs[BK_F][LDT];
    __shared__ float wt[6][BK_F][LDT];

    const int tid = threadIdx.x;
    const int bm0 = blockIdx.x * BM_F;
    const int jn0 = blockIdx.y * BN_F;
    const int lrw = tid >> 3;
    const int lcw = (tid & 7) << 2;
    const int ty = tid >> 4, tx = tid & 15;
    const int row0 = 2 * ty, col0 = 2 * tx;

    float aR[2][2] = {{0,0},{0,0}}, aZ[2][2] = {{0,0},{0,0}}, aN[2][2] = {{0,0},{0,0}};
    float hR[2][2] = {{0,0},{0,0}}, hZ[2][2] = {{0,0},{0,0}}, hN[2][2] = {{0,0},{0,0}};

    const int ldrow = bm0 + lrw;
    const bool rmaskld = (rst[ldrow] != 0);
    const float* xrow = x + (size_t)ldrow * 512;
    const float* hrow = h_prev + (size_t)ldrow * 512;

    for (int k0 = 0; k0 < 512; k0 += BK_F) {
        float4 xv = *(const float4*)(xrow + k0 + lcw);
        float4 hv = *(const float4*)(hrow + k0 + lcw);
        if (rmaskld) { hv.x = hv.y = hv.z = hv.w = 0.f; }
        const float* wi_row = Wi + (size_t)(k0 + lrw) * 1536;
        const float* wh_row = Wh_rz + (size_t)(k0 + lrw) * 1024;
        float4 w0v = *(const float4*)(wi_row + jn0 + lcw);
        float4 w1v = *(const float4*)(wi_row + 512 + jn0 + lcw);
        float4 w2v = *(const float4*)(wi_row + 1024 + jn0 + lcw);
        float4 w3v = *(const float4*)(wh_row + jn0 + lcw);
        float4 w4v = *(const float4*)(wh_row + 512 + jn0 + lcw);
        float4 w5v = *(const float4*)(Wh_n + (size_t)(k0 + lrw) * 512 + jn0 + lcw);
        __syncthreads();
        xs[lcw+0][lrw]=xv.x; xs[lcw+1][lrw]=xv.y; xs[lcw+2][lrw]=xv.z; xs[lcw+3][lrw]=xv.w;
        hs[lcw+0][lrw]=hv.x; hs[lcw+1][lrw]=hv.y; hs[lcw+2][lrw]=hv.z; hs[lcw+3][lrw]=hv.w;
        *(float4*)&wt[0][lrw][lcw] = w0v; *(float4*)&wt[1][lrw][lcw] = w1v;
        *(float4*)&wt[2][lrw][lcw] = w2v; *(float4*)&wt[3][lrw][lcw] = w3v;
        *(float4*)&wt[4][lrw][lcw] = w4v; *(float4*)&wt[5][lrw][lcw] = w5v;
        __syncthreads();
        #pragma unroll
        for (int kk = 0; kk < BK_F; ++kk) {
            float2 xa = *(const float2*)&xs[kk][row0];
            float2 ha = *(const float2*)&hs[kk][row0];
            float2 w0 = *(const float2*)&wt[0][kk][col0];
            float2 w1 = *(const float2*)&wt[1][kk][col0];
            float2 w2 = *(const float2*)&wt[2][kk][col0];
            float2 w3 = *(const float2*)&wt[3][kk][col0];
            float2 w4 = *(const float2*)&wt[4][kk][col0];
            float2 w5 = *(const float2*)&wt[5][kk][col0];
            aR[0][0]=fmaf(xa.x,w0.x,aR[0][0]); aR[0][1]=fmaf(xa.x,w0.y,aR[0][1]);
            aR[1][0]=fmaf(xa.y,w0.x,aR[1][0]); aR[1][1]=fmaf(xa.y,w0.y,aR[1][1]);
            aZ[0][0]=fmaf(xa.x,w1.x,aZ[0][0]); aZ[0][1]=fmaf(xa.x,w1.y,aZ[0][1]);
            aZ[1][0]=fmaf(xa.y,w1.x,aZ[1][0]); aZ[1][1]=fmaf(xa.y,w1.y,aZ[1][1]);
            aN[0][0]=fmaf(xa.x,w2.x,aN[0][0]); aN[0][1]=fmaf(xa.x,w2.y,aN[0][1]);
            aN[1][0]=fmaf(xa.y,w2.x,aN[1][0]); aN[1][1]=fmaf(xa.y,w2.y,aN[1][1]);
            hR[0][0]=fmaf(ha.x,w3.x,hR[0][0]); hR[0][1]=fmaf(ha.x,w3.y,hR[0][1]);
            hR[1][0]=fmaf(ha.y,w3.x,hR[1][0]); hR[1][1]=fmaf(ha.y,w3.y,hR[1][1]);
            hZ[0][0]=fmaf(ha.x,w4.x,hZ[0][0]); hZ[0][1]=fmaf(ha.x,w4.y,hZ[0][1]);
            hZ[1][0]=fmaf(ha.y,w4.x,hZ[1][0]); hZ[1][1]=fmaf(ha.y,w4.y,hZ[1][1]);
            hN[0][0]=fmaf(ha.x,w5.x,hN[0][0]); hN[0][1]=fmaf(ha.x,w5.y,hN[0][1]);
            hN[1][0]=fmaf(ha.y,w5.x,hN[1][0]); hN[1][1]=fmaf(ha.y,w5.y,hN[1][1]);
        }
    }
    #pragma unroll
    for (int ii = 0; ii < 2; ++ii) {
        const int b = bm0 + row0 + ii;
        const bool rm = (rst[b] != 0);
        #pragma unroll
        for (int jj = 0; jj < 2; ++jj) {
            const int jn = jn0 + col0 + jj;
            const float heff = rm ? 0.f : h_prev[(size_t)b * 512 + jn];
            const float r = sigf_(aR[ii][jj] + bi[jn] + hR[ii][jj]);
            const float z = sigf_(aZ[ii][jj] + bi[512 + jn] + hZ[ii][jj]);
            const float n = tanhf(aN[ii][jj] + bi[1024 + jn] + r * (hN[ii][jj] + bh_n[jn]));
            const float v = (1.f - z) * n + z * heff;
            h_out[(size_t)b * 512 + jn] = v;
            if (hT_out) hT_out[(size_t)b * 512 + jn] = v;
        }
    }
}

// ---------------------------------------------------------------------------
extern "C" void kernel_launch(void* const* d_in, const int* in_sizes, int n_in,
                              void* d_out, int out_size, void* d_ws, size_t ws_size,
                              hipStream_t stream) {
    const float* h0     = (const float*)d_in[0];
    const float* ins    = (const float*)d_in[1];
    const int*   resets = (const int*)  d_in[2];
    const float* Wi     = (const float*)d_in[3];
    const float* bi     = (const float*)d_in[4];
    const float* Wh_rz  = (const float*)d_in[5];
    const float* Wh_n   = (const float*)d_in[6];
    const float* bh_n   = (const float*)d_in[7];

    float* out = (float*)d_out;
    float* hT  = out;
    float* ys  = out + (size_t)B_SZ * HD;

    const size_t WPLANE = (size_t)3072 * 512;
    const size_t wbytes = WPLANE * 2 * sizeof(_Float16);   // 6.3 MB

    int CH = 0;
    const int cands[8] = {128, 64, 32, 16, 8, 4, 2, 1};
    for (int c = 0; c < 8; ++c) {
        size_t need = wbytes + (size_t)cands[c] * 512 * 1536 * sizeof(float);
        if (ws_size >= need) { CH = cands[c]; break; }
    }

    if (CH > 0) {
        _Float16* WT_hi = (_Float16*)d_ws;
        _Float16* WT_lo = WT_hi + WPLANE;
        float* gi = (float*)((char*)d_ws + wbytes);
        conv_w<<<dim3(8, 48), 256, 0, stream>>>(Wi, Wh_rz, Wh_n, WT_hi, WT_lo);
        for (int t0 = 0; t0 < T_STEPS; t0 += CH) {
            const int R = CH * 512;
            gi_gemm<<<dim3(R / 128, 24), 256, 0, stream>>>(
                ins + (size_t)t0 * 512 * 512, WT_hi, WT_lo, bi, gi);
            for (int t = t0; t < t0 + CH; ++t) {
                const float* hp = (t == 0) ? h0 : (ys + (size_t)(t - 1) * 512 * 512);
                float* ho = ys + (size_t)t * 512 * 512;
                gru_step_h<<<dim3(16, 16), 256, 0, stream>>>(
                    resets + (size_t)t * 512, hp, WT_hi, WT_lo,
                    gi + (size_t)(t - t0) * 512 * 1536,
                    bh_n, ho, (t == T_STEPS - 1) ? hT : nullptr);
            }
        }
    } else if (ws_size >= wbytes) {
        _Float16* WT_hi = (_Float16*)d_ws;
        _Float16* WT_lo = WT_hi + WPLANE;
        conv_w<<<dim3(8, 48), 256, 0, stream>>>(Wi, Wh_rz, Wh_n, WT_hi, WT_lo);
        for (int t = 0; t < T_STEPS; ++t) {
            const float* hp = (t == 0) ? h0 : (ys + (size_t)(t - 1) * 512 * 512);
            float* ho = ys + (size_t)t * 512 * 512;
            gru_fused<<<dim3(16, 8), 256, 0, stream>>>(
                ins + (size_t)t * 512 * 512, resets + (size_t)t * 512,
                hp, WT_hi, WT_lo, bi, bh_n,
                ho, (t == T_STEPS - 1) ? hT : nullptr);
        }
    } else {
        dim3 grid(B_SZ / BM_F, HD / BN_F);
        for (int t = 0; t < T_STEPS; ++t) {
            const float* hp = (t == 0) ? h0 : (ys + (size_t)(t - 1) * 512 * 512);
            float* ho = ys + (size_t)t * 512 * 512;
            gru_step_f32<<<grid, 256, 0, stream>>>(
                ins + (size_t)t * 512 * 512, resets + (size_t)t * 512,
                hp, Wi, bi, Wh_rz, Wh_n, bh_n,
                ho, (t == T_STEPS - 1) ? hT : nullptr);
        }
    }
}